// Round 1
// 4806.934 us; speedup vs baseline: 1.2015x; 1.2015x over previous
//
#include <hip/hip_runtime.h>

typedef unsigned short ushort_t;
typedef unsigned int uint_t;
typedef float f32x4 __attribute__((ext_vector_type(4)));
typedef short bf16x8 __attribute__((ext_vector_type(8)));

#define B_ 32
#define T_ 197
#define M_ 6304      // 32*197
#define M0_ 6272     // 32*196
#define DEPTH_ 12
#define NMAT_ 46
#define HBINS_ 16384

// ---------- ws layout (bytes) ----------
#define X_OFF    0ULL                      // f32 [6304,768]
#define H_OFF    19365888ULL               // bf16 [6304,768]
#define QKVB_OFF 29048832ULL               // bf16 [6304,2304]
#define O_OFF    58097664ULL               // bf16 [6304,768]
#define MID_OFF  67780608ULL               // bf16 [6304,3072]
#define WT_OFF   106512384ULL              // bf16 [<=3072*768] transposed weight
#define HIST_OFF 111230976ULL              // u32 [46*16384]  pass-1 histogram
#define H2_OFF   114245632ULL              // u32 [46*2*16384] pass-2 histograms
#define SUMS_OFF 120274944ULL              // f32 [46] (+pad)
#define SEL_OFF  120275200ULL              // u32 [46*4] bin1,below1,bin2,below2
#define PAR_OFF  120276224ULL              // f32 [46*2] thr, scale

__device__ __forceinline__ float b2f(ushort_t u) {
    return __uint_as_float(((uint_t)u) << 16);
}
__device__ __forceinline__ ushort_t f2b(float f) {
    uint_t u = __float_as_uint(f);
    u += 0x7FFFu + ((u >> 16) & 1u);   // RNE
    return (ushort_t)(u >> 16);
}
__device__ __forceinline__ float gelu_f(float v) {
    // 0.5*v*(1+tanh(u)) == v * sigmoid(2u); sigmoid form avoids libm tanhf.
    float u = 0.7978845608028654f * (v + 0.044715f * v * v * v);
    return v / (1.f + __expf(-2.f * u));
}

// async global->LDS 16B DMA (wave-uniform LDS base + lane*16)
__device__ __forceinline__ void gld_lds16(void* lds, const void* g) {
    __builtin_amdgcn_global_load_lds(
        (const __attribute__((address_space(1))) unsigned int*)g,
        (__attribute__((address_space(3))) unsigned int*)lds, 16, 0, 0);
}

__device__ __forceinline__ void mat_info(int m, const float* Wqkv, const float* Wo,
                                         const float* W1, const float* W2,
                                         const float** W, int* N) {
    if (m < 12)      { *W = Wqkv + (size_t)m * 1769472;        *N = 1769472; }
    else if (m < 24) { *W = Wo   + (size_t)(m - 12) * 589824;  *N = 589824; }
    else if (m < 35) { *W = W1   + (size_t)(m - 24) * 2359296; *N = 2359296; }
    else             { *W = W2   + (size_t)(m - 35) * 2359296; *N = 2359296; }
}
__device__ __forceinline__ int mat_n(int m) {
    if (m < 12) return 1769472;
    if (m < 24) return 589824;
    return 2359296;
}

// ---------- pass 1: histogram |w| bits[30:17] + sum|w| ----------
// Tiled 4096-float chunks: 4 independent dwordx4 loads/thread/iter for MLP.
// (all matrix sizes are multiples of 4096 floats)
__global__ __launch_bounds__(256) void hist1_kernel(const float* Wqkv, const float* Wo,
                                                    const float* W1, const float* W2,
                                                    uint_t* hist, float* sums) {
    __shared__ uint_t lh[HBINS_];
    int m = blockIdx.y;
    const float* W; int N;
    mat_info(m, Wqkv, Wo, W1, W2, &W, &N);
    int t = threadIdx.x;
    for (int i = t; i < HBINS_; i += 256) lh[i] = 0;
    __syncthreads();
    float s = 0.f;
    const float4* W4 = (const float4*)W;
    int ntile = N >> 12;                  // tiles of 1024 float4
    for (int tb = blockIdx.x; tb < ntile; tb += gridDim.x) {
        const float4* p = W4 + (size_t)tb * 1024 + t;
        float4 w0 = p[0];
        float4 w1 = p[256];
        float4 w2 = p[512];
        float4 w3 = p[768];
        float vs[16] = { w0.x, w0.y, w0.z, w0.w, w1.x, w1.y, w1.z, w1.w,
                         w2.x, w2.y, w2.z, w2.w, w3.x, w3.y, w3.z, w3.w };
        #pragma unroll
        for (int q = 0; q < 16; q++) {
            uint_t ub = __float_as_uint(vs[q]) & 0x7FFFFFFFu;
            s += __uint_as_float(ub);
            uint_t bin = ub >> 17;
            if (bin > 16383u) bin = 16383u;
            atomicAdd(&lh[bin], 1u);
        }
    }
    __syncthreads();
    uint_t* gh = hist + (size_t)m * HBINS_;
    for (int i = t; i < HBINS_; i += 256)
        if (lh[i]) atomicAdd(&gh[i], lh[i]);
    for (int off = 32; off > 0; off >>= 1) s += __shfl_down(s, off, 64);
    if ((t & 63) == 0) atomicAdd(&sums[m], s);
}

// ---------- select pass-1 bins containing ranks N/2, N/2+1 (1-based) ----------
__global__ __launch_bounds__(256) void sel1_kernel(const uint_t* hist, uint_t* sel) {
    int m = blockIdx.x, t = threadIdx.x;
    const uint_t* gh = hist + (size_t)m * HBINS_;
    int N = mat_n(m);
    uint_t own = 0;
    for (int i = 0; i < 64; i++) own += gh[t * 64 + i];
    __shared__ uint_t cs[256];
    cs[t] = own; __syncthreads();
    for (int o = 1; o < 256; o <<= 1) {
        uint_t vv = (t >= o) ? cs[t - o] : 0u;
        __syncthreads();
        cs[t] += vv;
        __syncthreads();
    }
    uint_t c = cs[t] - own;
    uint_t r1 = (uint_t)(N >> 1), r2 = r1 + 1;
    for (int i = 0; i < 64; i++) {
        uint_t hv = gh[t * 64 + i];
        if (hv) {
            uint_t bin = (uint_t)(t * 64 + i);
            if (r1 > c && r1 <= c + hv) { sel[m * 4 + 0] = bin; sel[m * 4 + 1] = c; }
            if (r2 > c && r2 <= c + hv) { sel[m * 4 + 2] = bin; sel[m * 4 + 3] = c; }
            c += hv;
        }
    }
}

// ---------- pass 2: histogram bits[16:3] of elements in the selected bins ----------
__global__ __launch_bounds__(256) void hist2_kernel(const float* Wqkv, const float* Wo,
                                                    const float* W1, const float* W2,
                                                    const uint_t* sel, uint_t* h2) {
    int m = blockIdx.y;
    const float* W; int N;
    mat_info(m, Wqkv, Wo, W1, W2, &W, &N);
    uint_t b1 = sel[m * 4 + 0], b2 = sel[m * 4 + 2];
    uint_t* ha = h2 + (size_t)m * 2 * HBINS_;
    uint_t* hb = ha + HBINS_;
    int t = threadIdx.x;
    const float4* W4 = (const float4*)W;
    int ntile = N >> 12;
    for (int tb = blockIdx.x; tb < ntile; tb += gridDim.x) {
        const float4* p = W4 + (size_t)tb * 1024 + t;
        float4 w0 = p[0];
        float4 w1 = p[256];
        float4 w2 = p[512];
        float4 w3 = p[768];
        float vs[16] = { w0.x, w0.y, w0.z, w0.w, w1.x, w1.y, w1.z, w1.w,
                         w2.x, w2.y, w2.z, w2.w, w3.x, w3.y, w3.z, w3.w };
        #pragma unroll
        for (int q = 0; q < 16; q++) {
            uint_t ub = __float_as_uint(vs[q]) & 0x7FFFFFFFu;
            uint_t bin = ub >> 17;
            uint_t sub = (ub >> 3) & 0x3FFFu;
            if (bin == b1) atomicAdd(&ha[sub], 1u);
            if (bin == b2 && b2 != b1) atomicAdd(&hb[sub], 1u);
        }
    }
}

// ---------- final select: reconstruct order stats, thr = midpoint, scale = mean ----------
__global__ __launch_bounds__(256) void sel2_kernel(const uint_t* h2, const uint_t* sel,
                                                   const float* sums, float* par) {
    int m = blockIdx.x, t = threadIdx.x;
    int N = mat_n(m);
    uint_t b1 = sel[m * 4 + 0], below1 = sel[m * 4 + 1];
    uint_t b2 = sel[m * 4 + 2], below2 = sel[m * 4 + 3];
    const uint_t* ha = h2 + (size_t)m * 2 * HBINS_;
    const uint_t* hb = (b2 == b1) ? ha : ha + HBINS_;
    uint_t r1 = (uint_t)(N >> 1) - below1;
    uint_t r2 = (uint_t)(N >> 1) + 1 - below2;
    __shared__ uint_t cs[256];
    __shared__ uint_t subs[2];
    uint_t own = 0;
    for (int i = 0; i < 64; i++) own += ha[t * 64 + i];
    cs[t] = own; __syncthreads();
    for (int o = 1; o < 256; o <<= 1) {
        uint_t vv = (t >= o) ? cs[t - o] : 0u;
        __syncthreads(); cs[t] += vv; __syncthreads();
    }
    uint_t c = cs[t] - own;
    for (int i = 0; i < 64; i++) {
        uint_t hv = ha[t * 64 + i];
        if (hv) {
            if (r1 > c && r1 <= c + hv) subs[0] = (uint_t)(t * 64 + i);
            c += hv;
        }
    }
    __syncthreads();
    own = 0;
    for (int i = 0; i < 64; i++) own += hb[t * 64 + i];
    cs[t] = own; __syncthreads();
    for (int o = 1; o < 256; o <<= 1) {
        uint_t vv = (t >= o) ? cs[t - o] : 0u;
        __syncthreads(); cs[t] += vv; __syncthreads();
    }
    c = cs[t] - own;
    for (int i = 0; i < 64; i++) {
        uint_t hv = hb[t * 64 + i];
        if (hv) {
            if (r2 > c && r2 <= c + hv) subs[1] = (uint_t)(t * 64 + i);
            c += hv;
        }
    }
    __syncthreads();
    if (t == 0) {
        float v1 = __uint_as_float((b1 << 17) | (subs[0] << 3) | 4u);
        float v2 = __uint_as_float((b2 << 17) | (subs[1] << 3) | 4u);
        par[2 * m]     = 0.5f * (v1 + v2);
        par[2 * m + 1] = sums[m] / (float)N;
    }
}

// ---------- quantize(+ternary) + transpose W[K,N](f32) -> Wt[N,K](bf16) ----------
__global__ __launch_bounds__(256) void trq_kernel(const float* W, ushort_t* Wt,
                                                  int K, int N, const float* params, int pidx) {
    __shared__ ushort_t tile[32][33];
    int n0 = blockIdx.x * 32, k0 = blockIdx.y * 32;
    int t = threadIdx.x;
    float thr = 0.f; ushort_t sq = 0;
    if (pidx >= 0) {
        thr = params[2 * pidx];
        sq  = f2b(params[2 * pidx + 1]);
    }
    int c = t & 31, r0 = t >> 5;
    for (int rr = r0; rr < 32; rr += 8) {
        float w = W[(size_t)(k0 + rr) * N + n0 + c];
        ushort_t u;
        if (pidx >= 0) {
            ushort_t sgn = (ushort_t)((__float_as_uint(w) >> 16) & 0x8000u);
            u = (fabsf(w) >= thr) ? (ushort_t)(sq | sgn) : (ushort_t)0;
        } else {
            u = f2b(w);
        }
        tile[rr][c] = u;
    }
    __syncthreads();
    int kk = t & 31, nr = t >> 5;
    for (int nn = nr; nn < 32; nn += 8)
        Wt[(size_t)(n0 + nn) * K + k0 + kk] = tile[kk][nn];
}

// ---------- patchify + patch LN -> bf16 ----------
__global__ __launch_bounds__(256) void patchify_kernel(const float* img, const float* g,
                                                       const float* b, ushort_t* A0) {
    int blk = blockIdx.x;
    int bb = blk / 196, p = blk % 196;
    int ph = p / 14, pw = p % 14;
    int t = threadIdx.x;
    float v[3];
    #pragma unroll
    for (int i = 0; i < 3; i++) {
        int d = t + i * 256;
        int c = d % 3, pix = d / 3, p2 = pix & 15, p1 = pix >> 4;
        size_t idx = (((size_t)(bb * 3 + c) * 224) + ph * 16 + p1) * 224 + pw * 16 + p2;
        v[i] = img[idx];
    }
    __shared__ float s1[256], s2[256];
    s1[t] = v[0] + v[1] + v[2];
    s2[t] = v[0] * v[0] + v[1] * v[1] + v[2] * v[2];
    __syncthreads();
    for (int o = 128; o > 0; o >>= 1) {
        if (t < o) { s1[t] += s1[t + o]; s2[t] += s2[t + o]; }
        __syncthreads();
    }
    float mu = s1[0] * (1.f / 768.f);
    float var = s2[0] * (1.f / 768.f) - mu * mu;
    float rs = rsqrtf(var + 1e-5f);
    #pragma unroll
    for (int i = 0; i < 3; i++) {
        int d = t + i * 256;
        A0[(size_t)blk * 768 + d] = f2b((v[i] - mu) * rs * g[d] + b[d]);
    }
}

// ---------- emb LN + cls + pos -> x (f32) ----------
__global__ __launch_bounds__(256) void assemble_kernel(const ushort_t* P, const float* cls,
                                                       const float* pos, const float* g,
                                                       const float* b, float* X) {
    int r = blockIdx.x;
    int bb = r / 197, tk = r % 197;
    int t = threadIdx.x;
    if (tk == 0) {
        #pragma unroll
        for (int i = 0; i < 3; i++) {
            int d = t + i * 256;
            X[(size_t)r * 768 + d] = cls[d] + pos[d];
        }
        return;
    }
    const ushort_t* pr = P + (size_t)(bb * 196 + tk - 1) * 768;
    float v[3];
    #pragma unroll
    for (int i = 0; i < 3; i++) v[i] = b2f(pr[t + i * 256]);
    __shared__ float s1[256], s2[256];
    s1[t] = v[0] + v[1] + v[2];
    s2[t] = v[0] * v[0] + v[1] * v[1] + v[2] * v[2];
    __syncthreads();
    for (int o = 128; o > 0; o >>= 1) {
        if (t < o) { s1[t] += s1[t + o]; s2[t] += s2[t + o]; }
        __syncthreads();
    }
    float mu = s1[0] * (1.f / 768.f);
    float var = s2[0] * (1.f / 768.f) - mu * mu;
    float rs = rsqrtf(var + 1e-5f);
    #pragma unroll
    for (int i = 0; i < 3; i++) {
        int d = t + i * 256;
        X[(size_t)r * 768 + d] =
            (v[i] - mu) * rs * g[d] + b[d] + pos[(size_t)tk * 768 + d];
    }
}

// ---------- LN: x(f32) -> bf16 h, or f32 (final output) ----------
__global__ __launch_bounds__(256) void ln_kernel(const float* X, ushort_t* Hb, float* Hf,
                                                 const float* g, const float* b) {
    int r = blockIdx.x, t = threadIdx.x;
    const float* xr = X + (size_t)r * 768;
    float v0 = xr[t], v1 = xr[t + 256], v2 = xr[t + 512];
    __shared__ float s1[256], s2[256];
    s1[t] = v0 + v1 + v2;
    s2[t] = v0 * v0 + v1 * v1 + v2 * v2;
    __syncthreads();
    for (int o = 128; o > 0; o >>= 1) {
        if (t < o) { s1[t] += s1[t + o]; s2[t] += s2[t + o]; }
        __syncthreads();
    }
    float mu = s1[0] * (1.f / 768.f);
    float var = s2[0] * (1.f / 768.f) - mu * mu;
    float rs = rsqrtf(var + 1e-5f);
    float o0 = (v0 - mu) * rs * g[t]       + b[t];
    float o1 = (v1 - mu) * rs * g[t + 256] + b[t + 256];
    float o2 = (v2 - mu) * rs * g[t + 512] + b[t + 512];
    if (Hf) {
        Hf[(size_t)r * 768 + t] = o0;
        Hf[(size_t)r * 768 + t + 256] = o1;
        Hf[(size_t)r * 768 + t + 512] = o2;
    } else {
        Hb[(size_t)r * 768 + t] = f2b(o0);
        Hb[(size_t)r * 768 + t + 256] = f2b(o1);
        Hb[(size_t)r * 768 + t + 512] = f2b(o2);
    }
}

// ---------- MFMA GEMM: C[M,N] = A[M,K](bf16) @ Bt[N,K]^T(bf16) + bias(f32) ----------
// m97 structure: 128x128 tile, BK=32, linear LDS [128][32], global_load_lds width=16.
// A-tail rows (M not multiple of 128) load a clamped (duplicate) row; their
// accumulators are garbage but the store mask (row < M) drops them.
__global__ __launch_bounds__(256) void gemm_kernel(const ushort_t* A, const ushort_t* Bt,
                                                   const float* bias, void* Cout,
                                                   const float* R, int M, int N, int K, int epi) {
    __shared__ ushort_t As[128 * 32];
    __shared__ ushort_t Bs[128 * 32];
    int t = threadIdx.x;
    int lane = t & 63, wave = t >> 6;
    int row0 = blockIdx.y * 128, col0 = blockIdx.x * 128;
    int wm = (wave >> 1) * 64, wn = (wave & 1) * 64;
    int fr = lane & 15, fq = lane >> 4;

    // staging: thread t covers row (t>>2) [+64 for second issue], 16B chunk (t&3)
    int srow = t >> 2;
    int scol = (t & 3) * 8;
    const ushort_t* gA0 = A + (size_t)min(row0 + srow, M - 1) * K + scol;
    const ushort_t* gA1 = A + (size_t)min(row0 + 64 + srow, M - 1) * K + scol;
    const ushort_t* gB0 = Bt + (size_t)(col0 + srow) * K + scol;
    const ushort_t* gB1 = Bt + (size_t)(col0 + 64 + srow) * K + scol;
    ushort_t* lA0 = &As[t * 8];          // == row srow, chunk (t&3): linear in wave-lane order
    ushort_t* lA1 = &As[2048 + t * 8];
    ushort_t* lB0 = &Bs[t * 8];
    ushort_t* lB1 = &Bs[2048 + t * 8];

    f32x4 acc[4][4];
    #pragma unroll
    for (int i = 0; i < 4; i++)
        #pragma unroll
        for (int j = 0; j < 4; j++)
            acc[i][j] = (f32x4){0.f, 0.f, 0.f, 0.f};

    for (int k0 = 0; k0 < K; k0 += 32) {
        gld_lds16(lA0, gA0 + k0);
        gld_lds16(lA1, gA1 + k0);
        gld_lds16(lB0, gB0 + k0);
        gld_lds16(lB1, gB1 + k0);
        __syncthreads();   // drains vmcnt (global_load_lds) before reads
        bf16x8 af[4], bfr[4];
        #pragma unroll
        for (int mt = 0; mt < 4; mt++)
            af[mt] = *(const bf16x8*)&As[(wm + mt * 16 + fr) * 32 + fq * 8];
        #pragma unroll
        for (int nt = 0; nt < 4; nt++)
            bfr[nt] = *(const bf16x8*)&Bs[(wn + nt * 16 + fr) * 32 + fq * 8];
        #pragma unroll
        for (int mt = 0; mt < 4; mt++)
            #pragma unroll
            for (int nt = 0; nt < 4; nt++)
                acc[mt][nt] = __builtin_amdgcn_mfma_f32_16x16x32_bf16(
                    af[mt], bfr[nt], acc[mt][nt], 0, 0, 0);
        __syncthreads();   // all waves done reading before next DMA overwrites
    }
    #pragma unroll
    for (int nt = 0; nt < 4; nt++) {
        int col = col0 + wn + nt * 16 + fr;
        float bv = bias[col];
        #pragma unroll
        for (int mt = 0; mt < 4; mt++) {
            #pragma unroll
            for (int gi = 0; gi < 4; gi++) {
                int row = row0 + wm + mt * 16 + fq * 4 + gi;
                if (row < M) {
                    float val = acc[mt][nt][gi] + bv;
                    if (epi == 1) val = gelu_f(val);
                    size_t off = (size_t)row * N + col;
                    if (epi == 2) ((float*)Cout)[off] = val + R[off];
                    else          ((ushort_t*)Cout)[off] = f2b(val);
                }
            }
        }
    }
}

// ---------- MFMA flash attention ----------
// grid (4 q-tiles, 384 bh), 4 waves, each wave = 16 q-rows.
// LDS: KbP = K rows [224][72] (reused as P [64][232] after barrier), Vt = V^T [64][232]
#define TPAD_ 224
#define KROW_ 72
#define VROW_ 232
__global__ __launch_bounds__(256) void attn_kernel(const ushort_t* qkv, ushort_t* O) {
    __shared__ ushort_t KbP[TPAD_ * KROW_];
    __shared__ ushort_t Vt[64 * VROW_];
    int qt = blockIdx.x;
    int bh = blockIdx.y;
    int bb = bh / 12, hh = bh % 12;
    int t = threadIdx.x, lane = t & 63, w = t >> 6;
    int q = lane >> 4, n = lane & 15;
    size_t base = (size_t)bb * 197 * 2304 + hh * 64;

    // stage K rows (row-major, zero-pad rows >=197)
    for (int e = t; e < TPAD_ * 8; e += 256) {
        int j = e >> 3, d8 = e & 7;
        uint4 kv = make_uint4(0u, 0u, 0u, 0u);
        if (j < 197) kv = *(const uint4*)(qkv + base + (size_t)j * 2304 + 768 + d8 * 8);
        *(uint4*)&KbP[j * KROW_ + d8 * 8] = kv;
    }
    // stage V transposed: Vt[d][j]
    for (int d8 = 0; d8 < 8; d8++) {
        int j = t;
        if (j < 197) {
            uint4 vv = *(const uint4*)(qkv + base + (size_t)j * 2304 + 1536 + d8 * 8);
            ushort_t tmp[8];
            *(uint4*)tmp = vv;
            #pragma unroll
            for (int i = 0; i < 8; i++) Vt[(d8 * 8 + i) * VROW_ + j] = tmp[i];
        }
    }
    // zero pad cols j=197..223 of Vt
    {
        int j = 197 + (t & 31);
        if (j < TPAD_)
            for (int d = t >> 5; d < 64; d += 8) Vt[d * VROW_ + j] = 0;
    }
    __syncthreads();

    // Q fragments for this wave's 16 rows (A layout: m=lane&15, k=quad*8+j)
    int i0 = qt * 64 + w * 16;
    bf16x8 qf[2];
    {
        int row = i0 + n;
        #pragma unroll
        for (int kc = 0; kc < 2; kc++) {
            uint4 qv = make_uint4(0u, 0u, 0u, 0u);
            if (row < 197)
                qv = *(const uint4*)(qkv + base + (size_t)row * 2304 + kc * 32 + q * 8);
            qf[kc] = *(bf16x8*)&qv;
        }
    }
    // S = Q K^T over 14 col tiles
    f32x4 sa[14];
    #pragma unroll
    for (int ct = 0; ct < 14; ct++) sa[ct] = (f32x4){0.f, 0.f, 0.f, 0.f};
    #pragma unroll
    for (int kc = 0; kc < 2; kc++) {
        #pragma unroll
        for (int ct = 0; ct < 14; ct++) {
            bf16x8 kf = *(const bf16x8*)&KbP[(ct * 16 + n) * KROW_ + kc * 32 + q * 8];
            sa[ct] = __builtin_amdgcn_mfma_f32_16x16x32_bf16(qf[kc], kf, sa[ct], 0, 0, 0);
        }
    }
    // softmax (rows r = q*4+gi spread over the 16 lanes n of this quad)
    float mx[4] = {-1e30f, -1e30f, -1e30f, -1e30f};
    #pragma unroll
    for (int ct = 0; ct < 14; ct++) {
        bool v = (ct * 16 + n) < 197;
        #pragma unroll
        for (int gi = 0; gi < 4; gi++) {
            float s = sa[ct][gi] * 0.125f;
            sa[ct][gi] = s;
            if (v) mx[gi] = fmaxf(mx[gi], s);
        }
    }
    #pragma unroll
    for (int msk = 1; msk < 16; msk <<= 1)
        #pragma unroll
        for (int gi = 0; gi < 4; gi++)
            mx[gi] = fmaxf(mx[gi], __shfl_xor(mx[gi], msk, 64));
    float sm[4] = {0.f, 0.f, 0.f, 0.f};
    #pragma unroll
    for (int ct = 0; ct < 14; ct++) {
        bool v = (ct * 16 + n) < 197;
        #pragma unroll
        for (int gi = 0; gi < 4; gi++) {
            float p = v ? __expf(sa[ct][gi] - mx[gi]) : 0.f;
            sa[ct][gi] = p;
            sm[gi] += p;
        }
    }
    #pragma unroll
    for (int msk = 1; msk < 16; msk <<= 1)
        #pragma unroll
        for (int gi = 0; gi < 4; gi++)
            sm[gi] += __shfl_xor(sm[gi], msk, 64);
    #pragma unroll
    for (int gi = 0; gi < 4; gi++) sm[gi] = 1.f / sm[gi];

    __syncthreads();   // all waves done reading K before P overwrites KbP

    // write P (C layout -> LDS rows), rows w*16 + q*4+gi
    #pragma unroll
    for (int ct = 0; ct < 14; ct++)
        #pragma unroll
        for (int gi = 0; gi < 4; gi++)
            KbP[(w * 16 + q * 4 + gi) * VROW_ + ct * 16 + n] = f2b(sa[ct][gi] * sm[gi]);

    // O = P V  (A = P rows m=lane&15, B = Vt rows n=out col)
    f32x4 oa[4];
    #pragma unroll
    for (int nt = 0; nt < 4; nt++) oa[nt] = (f32x4){0.f, 0.f, 0.f, 0.f};
    #pragma unroll
    for (int kc = 0; kc < 7; kc++) {
        bf16x8 pf = *(const bf16x8*)&KbP[(w * 16 + n) * VROW_ + kc * 32 + q * 8];
        #pragma unroll
        for (int nt = 0; nt < 4; nt++) {
            bf16x8 vf = *(const bf16x8*)&Vt[(nt * 16 + n) * VROW_ + kc * 32 + q * 8];
            oa[nt] = __builtin_amdgcn_mfma_f32_16x16x32_bf16(pf, vf, oa[nt], 0, 0, 0);
        }
    }
    #pragma unroll
    for (int nt = 0; nt < 4; nt++) {
        #pragma unroll
        for (int gi = 0; gi < 4; gi++) {
            int row = i0 + q * 4 + gi;
            if (row < 197)
                O[((size_t)bb * 197 + row) * 768 + hh * 64 + nt * 16 + n] = f2b(oa[nt][gi]);
        }
    }
}

extern "C" void kernel_launch(void* const* d_in, const int* in_sizes, int n_in,
                              void* d_out, int out_size, void* d_ws, size_t ws_size,
                              hipStream_t stream) {
    const float* img   = (const float*)d_in[0];
    const float* plg   = (const float*)d_in[1];
    const float* plb   = (const float*)d_in[2];
    const float* Wp    = (const float*)d_in[3];
    const float* bp    = (const float*)d_in[4];
    const float* elg   = (const float*)d_in[5];
    const float* elb   = (const float*)d_in[6];
    const float* pos   = (const float*)d_in[7];
    const float* cls   = (const float*)d_in[8];
    const float* l1g   = (const float*)d_in[9];
    const float* l1b   = (const float*)d_in[10];
    const float* Wqkv  = (const float*)d_in[11];
    const float* bqkv  = (const float*)d_in[12];
    const float* Wo    = (const float*)d_in[13];
    const float* bo    = (const float*)d_in[14];
    const float* l2g   = (const float*)d_in[15];
    const float* l2b   = (const float*)d_in[16];
    const float* W1    = (const float*)d_in[17];
    const float* b1    = (const float*)d_in[18];
    const float* W2    = (const float*)d_in[19];
    const float* b2    = (const float*)d_in[20];
    const float* ng    = (const float*)d_in[21];
    const float* nb    = (const float*)d_in[22];

    char* ws = (char*)d_ws;
    float*    x    = (float*)(ws + X_OFF);
    ushort_t* h    = (ushort_t*)(ws + H_OFF);
    ushort_t* qkvb = (ushort_t*)(ws + QKVB_OFF);
    ushort_t* o    = (ushort_t*)(ws + O_OFF);
    ushort_t* mid  = (ushort_t*)(ws + MID_OFF);
    ushort_t* wt   = (ushort_t*)(ws + WT_OFF);
    uint_t*   hist = (uint_t*)(ws + HIST_OFF);
    uint_t*   h2   = (uint_t*)(ws + H2_OFF);
    float*    sums = (float*)(ws + SUMS_OFF);
    uint_t*   sel  = (uint_t*)(ws + SEL_OFF);
    float*    par  = (float*)(ws + PAR_OFF);

    hipMemsetAsync(ws + HIST_OFF, 0, SEL_OFF - HIST_OFF, stream);

    hist1_kernel<<<dim3(64, NMAT_), 256, 0, stream>>>(Wqkv, Wo, W1, W2, hist, sums);
    sel1_kernel<<<NMAT_, 256, 0, stream>>>(hist, sel);
    hist2_kernel<<<dim3(64, NMAT_), 256, 0, stream>>>(Wqkv, Wo, W1, W2, sel, h2);
    sel2_kernel<<<NMAT_, 256, 0, stream>>>(h2, sel, sums, par);

    patchify_kernel<<<M0_, 256, 0, stream>>>(img, plg, plb, h);
    trq_kernel<<<dim3(768 / 32, 768 / 32), 256, 0, stream>>>(Wp, wt, 768, 768, par, -1);
    gemm_kernel<<<dim3(6, 49), 256, 0, stream>>>(h, wt, bp, o, nullptr, M0_, 768, 768, 0);
    assemble_kernel<<<M_, 256, 0, stream>>>(o, cls, pos, elg, elb, x);

    for (int i = 0; i < DEPTH_; i++) {
        ln_kernel<<<M_, 256, 0, stream>>>(x, h, nullptr, l1g + i * 768, l1b + i * 768);
        trq_kernel<<<dim3(2304 / 32, 768 / 32), 256, 0, stream>>>(
            Wqkv + (size_t)i * 1769472, wt, 768, 2304, par, i);
        gemm_kernel<<<dim3(18, 50), 256, 0, stream>>>(h, wt, bqkv + i * 2304, qkvb, nullptr,
                                                      M_, 2304, 768, 0);
        attn_kernel<<<dim3(4, B_ * 12), 256, 0, stream>>>(qkvb, o);
        trq_kernel<<<dim3(768 / 32, 768 / 32), 256, 0, stream>>>(
            Wo + (size_t)i * 589824, wt, 768, 768, par, 12 + i);
        gemm_kernel<<<dim3(6, 50), 256, 0, stream>>>(o, wt, bo + i * 768, x, x,
                                                     M_, 768, 768, 2);
        ln_kernel<<<M_, 256, 0, stream>>>(x, h, nullptr, l2g + i * 768, l2b + i * 768);
        trq_kernel<<<dim3(3072 / 32, 768 / 32), 256, 0, stream>>>(
            W1 + (size_t)i * 2359296, wt, 768, 3072, par, (i < 11) ? 24 + i : -1);
        gemm_kernel<<<dim3(24, 50), 256, 0, stream>>>(h, wt, b1 + i * 3072, mid, nullptr,
                                                      M_, 3072, 768, 1);
        trq_kernel<<<dim3(768 / 32, 3072 / 32), 256, 0, stream>>>(
            W2 + (size_t)i * 2359296, wt, 3072, 768, par, (i < 11) ? 35 + i : -1);
        gemm_kernel<<<dim3(6, 50), 256, 0, stream>>>(mid, wt, b2 + i * 768, x, x,
                                                     M_, 768, 3072, 2);
    }

    ln_kernel<<<M_, 256, 0, stream>>>(x, nullptr, (float*)d_out, ng, nb);
}

// Round 3
// 4275.172 us; speedup vs baseline: 1.3510x; 1.1244x over previous
//
#include <hip/hip_runtime.h>

typedef unsigned short ushort_t;
typedef unsigned int uint_t;
typedef float f32x4 __attribute__((ext_vector_type(4)));
typedef short bf16x8 __attribute__((ext_vector_type(8)));

#define B_ 32
#define T_ 197
#define M_ 6304      // 32*197
#define M0_ 6272     // 32*196
#define DEPTH_ 12
#define NMAT_ 46
#define HBINS_ 16384

// ---------- ws layout (bytes) ----------
#define X_OFF    0ULL                      // f32 [6304,768]
#define H_OFF    19365888ULL               // bf16 [6304,768]
#define QKVB_OFF 29048832ULL               // bf16 [6304,2304]
#define O_OFF    58097664ULL               // bf16 [6304,768]
#define MID_OFF  67780608ULL               // bf16 [6304,3072]
#define WT_OFF   106512384ULL              // bf16 [<=3072*768] transposed weight
#define HIST_OFF 111230976ULL              // u32 [46*16384]  pass-1 histogram
#define H2_OFF   114245632ULL              // u32 [46*2*16384] pass-2 histograms
#define SUMS_OFF 120274944ULL              // f32 [46] (+pad)
#define SEL_OFF  120275200ULL              // u32 [46*4] bin1,below1,bin2,below2
#define PAR_OFF  120276224ULL              // f32 [46*2] thr, scale

__device__ __forceinline__ float b2f(ushort_t u) {
    return __uint_as_float(((uint_t)u) << 16);
}
__device__ __forceinline__ ushort_t f2b(float f) {
    uint_t u = __float_as_uint(f);
    u += 0x7FFFu + ((u >> 16) & 1u);   // RNE
    return (ushort_t)(u >> 16);
}
__device__ __forceinline__ float gelu_f(float v) {
    // 0.5*v*(1+tanh(u)) == v * sigmoid(2u); sigmoid form avoids libm tanhf.
    float u = 0.7978845608028654f * (v + 0.044715f * v * v * v);
    return v / (1.f + __expf(-2.f * u));
}

// async global->LDS 16B DMA (wave-uniform LDS base + lane*16)
__device__ __forceinline__ void gld_lds16(void* lds, const void* g) {
    __builtin_amdgcn_global_load_lds(
        (const __attribute__((address_space(1))) unsigned int*)g,
        (__attribute__((address_space(3))) unsigned int*)lds, 16, 0, 0);
}

__device__ __forceinline__ void mat_info(int m, const float* Wqkv, const float* Wo,
                                         const float* W1, const float* W2,
                                         const float** W, int* N) {
    if (m < 12)      { *W = Wqkv + (size_t)m * 1769472;        *N = 1769472; }
    else if (m < 24) { *W = Wo   + (size_t)(m - 12) * 589824;  *N = 589824; }
    else if (m < 35) { *W = W1   + (size_t)(m - 24) * 2359296; *N = 2359296; }
    else             { *W = W2   + (size_t)(m - 35) * 2359296; *N = 2359296; }
}
__device__ __forceinline__ int mat_n(int m) {
    if (m < 12) return 1769472;
    if (m < 24) return 589824;
    return 2359296;
}

// ---------- pass 1: histogram |w| bits[30:17] + sum|w| ----------
// 2-deep software pipeline (prefetch tile t+1 during processing of t) +
// packed 2x u16 counts per u32 word (per-block per-bin count < 37K, u16-safe)
// so LDS = 32 KiB -> ~5 blocks/CU instead of 2.
__global__ __launch_bounds__(256) void hist1_kernel(const float* Wqkv, const float* Wo,
                                                    const float* W1, const float* W2,
                                                    uint_t* hist, float* sums) {
    __shared__ uint_t lh[HBINS_ / 2];   // 2 bins per word: bin 2i low16, 2i+1 high16
    int m = blockIdx.y;
    const float* W; int N;
    mat_info(m, Wqkv, Wo, W1, W2, &W, &N);
    int t = threadIdx.x;
    for (int i = t; i < HBINS_ / 2; i += 256) lh[i] = 0;
    __syncthreads();
    float s = 0.f;
    const float4* W4 = (const float4*)W;
    int ntile = N >> 12;                  // tiles of 1024 float4
    int tb = blockIdx.x;
    float4 c0 = {}, c1 = {}, c2 = {}, c3 = {};
    if (tb < ntile) {
        const float4* p = W4 + (size_t)tb * 1024 + t;
        c0 = p[0]; c1 = p[256]; c2 = p[512]; c3 = p[768];
    }
    while (tb < ntile) {
        int nx = tb + gridDim.x;
        float4 n0 = {}, n1 = {}, n2 = {}, n3 = {};
        if (nx < ntile) {
            const float4* p = W4 + (size_t)nx * 1024 + t;
            n0 = p[0]; n1 = p[256]; n2 = p[512]; n3 = p[768];
        }
        float vs[16] = { c0.x, c0.y, c0.z, c0.w, c1.x, c1.y, c1.z, c1.w,
                         c2.x, c2.y, c2.z, c2.w, c3.x, c3.y, c3.z, c3.w };
        #pragma unroll
        for (int q = 0; q < 16; q++) {
            uint_t ub = __float_as_uint(vs[q]) & 0x7FFFFFFFu;
            s += __uint_as_float(ub);
            uint_t bin = ub >> 17;
            atomicAdd(&lh[bin >> 1], 1u << ((bin & 1u) << 4));
        }
        c0 = n0; c1 = n1; c2 = n2; c3 = n3;
        tb = nx;
    }
    __syncthreads();
    uint_t* gh = hist + (size_t)m * HBINS_;
    for (int i = t; i < HBINS_ / 2; i += 256) {
        uint_t v = lh[i];
        if (v & 0xFFFFu) atomicAdd(&gh[2 * i], v & 0xFFFFu);
        if (v >> 16)     atomicAdd(&gh[2 * i + 1], v >> 16);
    }
    for (int off = 32; off > 0; off >>= 1) s += __shfl_down(s, off, 64);
    if ((t & 63) == 0) atomicAdd(&sums[m], s);
}

// ---------- select pass-1 bins containing ranks N/2, N/2+1 (1-based) ----------
__global__ __launch_bounds__(256) void sel1_kernel(const uint_t* hist, uint_t* sel) {
    int m = blockIdx.x, t = threadIdx.x;
    const uint_t* gh = hist + (size_t)m * HBINS_;
    int N = mat_n(m);
    uint_t own = 0;
    for (int i = 0; i < 64; i++) own += gh[t * 64 + i];
    __shared__ uint_t cs[256];
    cs[t] = own; __syncthreads();
    for (int o = 1; o < 256; o <<= 1) {
        uint_t vv = (t >= o) ? cs[t - o] : 0u;
        __syncthreads();
        cs[t] += vv;
        __syncthreads();
    }
    uint_t c = cs[t] - own;
    uint_t r1 = (uint_t)(N >> 1), r2 = r1 + 1;
    for (int i = 0; i < 64; i++) {
        uint_t hv = gh[t * 64 + i];
        if (hv) {
            uint_t bin = (uint_t)(t * 64 + i);
            if (r1 > c && r1 <= c + hv) { sel[m * 4 + 0] = bin; sel[m * 4 + 1] = c; }
            if (r2 > c && r2 <= c + hv) { sel[m * 4 + 2] = bin; sel[m * 4 + 3] = c; }
            c += hv;
        }
    }
}

// ---------- pass 2: histogram bits[16:3] of elements in the selected bins ----------
__global__ __launch_bounds__(256) void hist2_kernel(const float* Wqkv, const float* Wo,
                                                    const float* W1, const float* W2,
                                                    const uint_t* sel, uint_t* h2) {
    int m = blockIdx.y;
    const float* W; int N;
    mat_info(m, Wqkv, Wo, W1, W2, &W, &N);
    uint_t b1 = sel[m * 4 + 0], b2 = sel[m * 4 + 2];
    uint_t* ha = h2 + (size_t)m * 2 * HBINS_;
    uint_t* hb = ha + HBINS_;
    int t = threadIdx.x;
    const float4* W4 = (const float4*)W;
    int ntile = N >> 12;
    int tb = blockIdx.x;
    float4 c0 = {}, c1 = {}, c2 = {}, c3 = {};
    if (tb < ntile) {
        const float4* p = W4 + (size_t)tb * 1024 + t;
        c0 = p[0]; c1 = p[256]; c2 = p[512]; c3 = p[768];
    }
    while (tb < ntile) {
        int nx = tb + gridDim.x;
        float4 n0 = {}, n1 = {}, n2 = {}, n3 = {};
        if (nx < ntile) {
            const float4* p = W4 + (size_t)nx * 1024 + t;
            n0 = p[0]; n1 = p[256]; n2 = p[512]; n3 = p[768];
        }
        float vs[16] = { c0.x, c0.y, c0.z, c0.w, c1.x, c1.y, c1.z, c1.w,
                         c2.x, c2.y, c2.z, c2.w, c3.x, c3.y, c3.z, c3.w };
        #pragma unroll
        for (int q = 0; q < 16; q++) {
            uint_t ub = __float_as_uint(vs[q]) & 0x7FFFFFFFu;
            uint_t bin = ub >> 17;
            uint_t sub = (ub >> 3) & 0x3FFFu;
            if (bin == b1) atomicAdd(&ha[sub], 1u);
            if (bin == b2 && b2 != b1) atomicAdd(&hb[sub], 1u);
        }
        c0 = n0; c1 = n1; c2 = n2; c3 = n3;
        tb = nx;
    }
}

// ---------- final select: reconstruct order stats, thr = midpoint, scale = mean ----------
__global__ __launch_bounds__(256) void sel2_kernel(const uint_t* h2, const uint_t* sel,
                                                   const float* sums, float* par) {
    int m = blockIdx.x, t = threadIdx.x;
    int N = mat_n(m);
    uint_t b1 = sel[m * 4 + 0], below1 = sel[m * 4 + 1];
    uint_t b2 = sel[m * 4 + 2], below2 = sel[m * 4 + 3];
    const uint_t* ha = h2 + (size_t)m * 2 * HBINS_;
    const uint_t* hb = (b2 == b1) ? ha : ha + HBINS_;
    uint_t r1 = (uint_t)(N >> 1) - below1;
    uint_t r2 = (uint_t)(N >> 1) + 1 - below2;
    __shared__ uint_t cs[256];
    __shared__ uint_t subs[2];
    uint_t own = 0;
    for (int i = 0; i < 64; i++) own += ha[t * 64 + i];
    cs[t] = own; __syncthreads();
    for (int o = 1; o < 256; o <<= 1) {
        uint_t vv = (t >= o) ? cs[t - o] : 0u;
        __syncthreads(); cs[t] += vv; __syncthreads();
    }
    uint_t c = cs[t] - own;
    for (int i = 0; i < 64; i++) {
        uint_t hv = ha[t * 64 + i];
        if (hv) {
            if (r1 > c && r1 <= c + hv) subs[0] = (uint_t)(t * 64 + i);
            c += hv;
        }
    }
    __syncthreads();
    own = 0;
    for (int i = 0; i < 64; i++) own += hb[t * 64 + i];
    cs[t] = own; __syncthreads();
    for (int o = 1; o < 256; o <<= 1) {
        uint_t vv = (t >= o) ? cs[t - o] : 0u;
        __syncthreads(); cs[t] += vv; __syncthreads();
    }
    c = cs[t] - own;
    for (int i = 0; i < 64; i++) {
        uint_t hv = hb[t * 64 + i];
        if (hv) {
            if (r2 > c && r2 <= c + hv) subs[1] = (uint_t)(t * 64 + i);
            c += hv;
        }
    }
    __syncthreads();
    if (t == 0) {
        float v1 = __uint_as_float((b1 << 17) | (subs[0] << 3) | 4u);
        float v2 = __uint_as_float((b2 << 17) | (subs[1] << 3) | 4u);
        par[2 * m]     = 0.5f * (v1 + v2);
        par[2 * m + 1] = sums[m] / (float)N;
    }
}

// ---------- quantize(+ternary) + transpose W[K,N](f32) -> Wt[N,K](bf16) ----------
__global__ __launch_bounds__(256) void trq_kernel(const float* W, ushort_t* Wt,
                                                  int K, int N, const float* params, int pidx) {
    __shared__ ushort_t tile[32][33];
    int n0 = blockIdx.x * 32, k0 = blockIdx.y * 32;
    int t = threadIdx.x;
    float thr = 0.f; ushort_t sq = 0;
    if (pidx >= 0) {
        thr = params[2 * pidx];
        sq  = f2b(params[2 * pidx + 1]);
    }
    int c = t & 31, r0 = t >> 5;
    for (int rr = r0; rr < 32; rr += 8) {
        float w = W[(size_t)(k0 + rr) * N + n0 + c];
        ushort_t u;
        if (pidx >= 0) {
            ushort_t sgn = (ushort_t)((__float_as_uint(w) >> 16) & 0x8000u);
            u = (fabsf(w) >= thr) ? (ushort_t)(sq | sgn) : (ushort_t)0;
        } else {
            u = f2b(w);
        }
        tile[rr][c] = u;
    }
    __syncthreads();
    int kk = t & 31, nr = t >> 5;
    for (int nn = nr; nn < 32; nn += 8)
        Wt[(size_t)(n0 + nn) * K + k0 + kk] = tile[kk][nn];
}

// ---------- patchify + patch LN -> bf16 ----------
__global__ __launch_bounds__(256) void patchify_kernel(const float* img, const float* g,
                                                       const float* b, ushort_t* A0) {
    int blk = blockIdx.x;
    int bb = blk / 196, p = blk % 196;
    int ph = p / 14, pw = p % 14;
    int t = threadIdx.x;
    float v[3];
    #pragma unroll
    for (int i = 0; i < 3; i++) {
        int d = t + i * 256;
        int c = d % 3, pix = d / 3, p2 = pix & 15, p1 = pix >> 4;
        size_t idx = (((size_t)(bb * 3 + c) * 224) + ph * 16 + p1) * 224 + pw * 16 + p2;
        v[i] = img[idx];
    }
    __shared__ float s1[256], s2[256];
    s1[t] = v[0] + v[1] + v[2];
    s2[t] = v[0] * v[0] + v[1] * v[1] + v[2] * v[2];
    __syncthreads();
    for (int o = 128; o > 0; o >>= 1) {
        if (t < o) { s1[t] += s1[t + o]; s2[t] += s2[t + o]; }
        __syncthreads();
    }
    float mu = s1[0] * (1.f / 768.f);
    float var = s2[0] * (1.f / 768.f) - mu * mu;
    float rs = rsqrtf(var + 1e-5f);
    #pragma unroll
    for (int i = 0; i < 3; i++) {
        int d = t + i * 256;
        A0[(size_t)blk * 768 + d] = f2b((v[i] - mu) * rs * g[d] + b[d]);
    }
}

// ---------- emb LN + cls + pos -> x (f32) ----------
__global__ __launch_bounds__(256) void assemble_kernel(const ushort_t* P, const float* cls,
                                                       const float* pos, const float* g,
                                                       const float* b, float* X) {
    int r = blockIdx.x;
    int bb = r / 197, tk = r % 197;
    int t = threadIdx.x;
    if (tk == 0) {
        #pragma unroll
        for (int i = 0; i < 3; i++) {
            int d = t + i * 256;
            X[(size_t)r * 768 + d] = cls[d] + pos[d];
        }
        return;
    }
    const ushort_t* pr = P + (size_t)(bb * 196 + tk - 1) * 768;
    float v[3];
    #pragma unroll
    for (int i = 0; i < 3; i++) v[i] = b2f(pr[t + i * 256]);
    __shared__ float s1[256], s2[256];
    s1[t] = v[0] + v[1] + v[2];
    s2[t] = v[0] * v[0] + v[1] * v[1] + v[2] * v[2];
    __syncthreads();
    for (int o = 128; o > 0; o >>= 1) {
        if (t < o) { s1[t] += s1[t + o]; s2[t] += s2[t + o]; }
        __syncthreads();
    }
    float mu = s1[0] * (1.f / 768.f);
    float var = s2[0] * (1.f / 768.f) - mu * mu;
    float rs = rsqrtf(var + 1e-5f);
    #pragma unroll
    for (int i = 0; i < 3; i++) {
        int d = t + i * 256;
        X[(size_t)r * 768 + d] =
            (v[i] - mu) * rs * g[d] + b[d] + pos[(size_t)tk * 768 + d];
    }
}

// ---------- LN: x(f32) -> bf16 h, or f32 (final output) ----------
__global__ __launch_bounds__(256) void ln_kernel(const float* X, ushort_t* Hb, float* Hf,
                                                 const float* g, const float* b) {
    int r = blockIdx.x, t = threadIdx.x;
    const float* xr = X + (size_t)r * 768;
    float v0 = xr[t], v1 = xr[t + 256], v2 = xr[t + 512];
    __shared__ float s1[256], s2[256];
    s1[t] = v0 + v1 + v2;
    s2[t] = v0 * v0 + v1 * v1 + v2 * v2;
    __syncthreads();
    for (int o = 128; o > 0; o >>= 1) {
        if (t < o) { s1[t] += s1[t + o]; s2[t] += s2[t + o]; }
        __syncthreads();
    }
    float mu = s1[0] * (1.f / 768.f);
    float var = s2[0] * (1.f / 768.f) - mu * mu;
    float rs = rsqrtf(var + 1e-5f);
    float o0 = (v0 - mu) * rs * g[t]       + b[t];
    float o1 = (v1 - mu) * rs * g[t + 256] + b[t + 256];
    float o2 = (v2 - mu) * rs * g[t + 512] + b[t + 512];
    if (Hf) {
        Hf[(size_t)r * 768 + t] = o0;
        Hf[(size_t)r * 768 + t + 256] = o1;
        Hf[(size_t)r * 768 + t + 512] = o2;
    } else {
        Hb[(size_t)r * 768 + t] = f2b(o0);
        Hb[(size_t)r * 768 + t + 256] = f2b(o1);
        Hb[(size_t)r * 768 + t + 512] = f2b(o2);
    }
}

// ---------- MFMA GEMM: C[M,N] = A[M,K](bf16) @ Bt[N,K]^T(bf16) + bias(f32) ----------
// 2-phase double-buffered pipeline (T3 minimum recipe): issue STAGE(next tile)
// BEFORE ds_read+MFMA of current tile; single drain-barrier per K-step so the
// in-flight loads overlap the MFMA work. BM=128, BN template (128 or 64), BK=32.
// A-tail rows (M not multiple of 128) load a clamped (duplicate) row; their
// accumulators are garbage but the store mask (row < M) drops them.
template<int BN>
__global__ __launch_bounds__(256) void gemm_kernel(const ushort_t* A, const ushort_t* Bt,
                                                   const float* bias, void* Cout,
                                                   const float* R, int M, int N, int K, int epi) {
    constexpr int NT = BN / 32;              // col fragments per wave (4 or 2)
    __shared__ ushort_t As[2][128 * 32];
    __shared__ ushort_t Bs[2][BN * 32];
    int t = threadIdx.x;
    int lane = t & 63, wave = t >> 6;
    int row0 = blockIdx.y * 128, col0 = blockIdx.x * BN;
    int wm = (wave >> 1) * 64, wn = (wave & 1) * (BN / 2);
    int fr = lane & 15, fq = lane >> 4;

    // staging: thread t covers row (t>>2) [+64 for second issue], 16B chunk (t&3)
    int srow = t >> 2;
    int scol = (t & 3) * 8;
    const ushort_t* gA0 = A + (size_t)min(row0 + srow, M - 1) * K + scol;
    const ushort_t* gA1 = A + (size_t)min(row0 + 64 + srow, M - 1) * K + scol;
    const ushort_t* gB0 = Bt + (size_t)(col0 + srow) * K + scol;
    const ushort_t* gB1 = (BN == 128)
        ? Bt + (size_t)(col0 + 64 + srow) * K + scol : gB0;

    f32x4 acc[4][NT];
    #pragma unroll
    for (int i = 0; i < 4; i++)
        #pragma unroll
        for (int j = 0; j < NT; j++)
            acc[i][j] = (f32x4){0.f, 0.f, 0.f, 0.f};

    // prologue: stage tile 0
    gld_lds16(&As[0][t * 8], gA0);
    gld_lds16(&As[0][2048 + t * 8], gA1);
    gld_lds16(&Bs[0][t * 8], gB0);
    if (BN == 128) gld_lds16(&Bs[0][2048 + t * 8], gB1);
    __syncthreads();   // drains vmcnt(0): tile 0 resident

    int cur = 0;
    for (int k0 = 0; k0 < K; k0 += 32) {
        int kn = k0 + 32;
        if (kn < K) {  // issue next-tile DMA before consuming current tile
            gld_lds16(&As[cur ^ 1][t * 8], gA0 + kn);
            gld_lds16(&As[cur ^ 1][2048 + t * 8], gA1 + kn);
            gld_lds16(&Bs[cur ^ 1][t * 8], gB0 + kn);
            if (BN == 128) gld_lds16(&Bs[cur ^ 1][2048 + t * 8], gB1 + kn);
        }
        bf16x8 af[4], bfr[NT];
        #pragma unroll
        for (int mt = 0; mt < 4; mt++)
            af[mt] = *(const bf16x8*)&As[cur][(wm + mt * 16 + fr) * 32 + fq * 8];
        #pragma unroll
        for (int nt = 0; nt < NT; nt++)
            bfr[nt] = *(const bf16x8*)&Bs[cur][(wn + nt * 16 + fr) * 32 + fq * 8];
        #pragma unroll
        for (int mt = 0; mt < 4; mt++)
            #pragma unroll
            for (int nt = 0; nt < NT; nt++)
                acc[mt][nt] = __builtin_amdgcn_mfma_f32_16x16x32_bf16(
                    af[mt], bfr[nt], acc[mt][nt], 0, 0, 0);
        __syncthreads();   // drains vmcnt(0)+lgkmcnt(0): next tile resident, cur free
        cur ^= 1;
    }
    #pragma unroll
    for (int nt = 0; nt < NT; nt++) {
        int col = col0 + wn + nt * 16 + fr;
        float bv = bias[col];
        #pragma unroll
        for (int mt = 0; mt < 4; mt++) {
            #pragma unroll
            for (int gi = 0; gi < 4; gi++) {
                int row = row0 + wm + mt * 16 + fq * 4 + gi;
                if (row < M) {
                    float val = acc[mt][nt][gi] + bv;
                    if (epi == 1) val = gelu_f(val);
                    size_t off = (size_t)row * N + col;
                    if (epi == 2) ((float*)Cout)[off] = val + R[off];
                    else          ((ushort_t*)Cout)[off] = f2b(val);
                }
            }
        }
    }
}

// ---------- MFMA flash attention ----------
// grid (4 q-tiles, 384 bh), 4 waves, each wave = 16 q-rows.
// LDS: KbP = K rows [224][72] (reused as P [64][232] after barrier), Vt = V^T [64][232]
#define TPAD_ 224
#define KROW_ 72
#define VROW_ 232
__global__ __launch_bounds__(256) void attn_kernel(const ushort_t* qkv, ushort_t* O) {
    __shared__ ushort_t KbP[TPAD_ * KROW_];
    __shared__ ushort_t Vt[64 * VROW_];
    int qt = blockIdx.x;
    int bh = blockIdx.y;
    int bb = bh / 12, hh = bh % 12;
    int t = threadIdx.x, lane = t & 63, w = t >> 6;
    int q = lane >> 4, n = lane & 15;
    size_t base = (size_t)bb * 197 * 2304 + hh * 64;

    // stage K rows (row-major, zero-pad rows >=197)
    for (int e = t; e < TPAD_ * 8; e += 256) {
        int j = e >> 3, d8 = e & 7;
        uint4 kv = make_uint4(0u, 0u, 0u, 0u);
        if (j < 197) kv = *(const uint4*)(qkv + base + (size_t)j * 2304 + 768 + d8 * 8);
        *(uint4*)&KbP[j * KROW_ + d8 * 8] = kv;
    }
    // stage V transposed: Vt[d][j]
    for (int d8 = 0; d8 < 8; d8++) {
        int j = t;
        if (j < 197) {
            uint4 vv = *(const uint4*)(qkv + base + (size_t)j * 2304 + 1536 + d8 * 8);
            ushort_t tmp[8];
            *(uint4*)tmp = vv;
            #pragma unroll
            for (int i = 0; i < 8; i++) Vt[(d8 * 8 + i) * VROW_ + j] = tmp[i];
        }
    }
    // zero pad cols j=197..223 of Vt
    {
        int j = 197 + (t & 31);
        if (j < TPAD_)
            for (int d = t >> 5; d < 64; d += 8) Vt[d * VROW_ + j] = 0;
    }
    __syncthreads();

    // Q fragments for this wave's 16 rows (A layout: m=lane&15, k=quad*8+j)
    int i0 = qt * 64 + w * 16;
    bf16x8 qf[2];
    {
        int row = i0 + n;
        #pragma unroll
        for (int kc = 0; kc < 2; kc++) {
            uint4 qv = make_uint4(0u, 0u, 0u, 0u);
            if (row < 197)
                qv = *(const uint4*)(qkv + base + (size_t)row * 2304 + kc * 32 + q * 8);
            qf[kc] = *(bf16x8*)&qv;
        }
    }
    // S = Q K^T over 14 col tiles
    f32x4 sa[14];
    #pragma unroll
    for (int ct = 0; ct < 14; ct++) sa[ct] = (f32x4){0.f, 0.f, 0.f, 0.f};
    #pragma unroll
    for (int kc = 0; kc < 2; kc++) {
        #pragma unroll
        for (int ct = 0; ct < 14; ct++) {
            bf16x8 kf = *(const bf16x8*)&KbP[(ct * 16 + n) * KROW_ + kc * 32 + q * 8];
            sa[ct] = __builtin_amdgcn_mfma_f32_16x16x32_bf16(qf[kc], kf, sa[ct], 0, 0, 0);
        }
    }
    // softmax (rows r = q*4+gi spread over the 16 lanes n of this quad)
    float mx[4] = {-1e30f, -1e30f, -1e30f, -1e30f};
    #pragma unroll
    for (int ct = 0; ct < 14; ct++) {
        bool v = (ct * 16 + n) < 197;
        #pragma unroll
        for (int gi = 0; gi < 4; gi++) {
            float s = sa[ct][gi] * 0.125f;
            sa[ct][gi] = s;
            if (v) mx[gi] = fmaxf(mx[gi], s);
        }
    }
    #pragma unroll
    for (int msk = 1; msk < 16; msk <<= 1)
        #pragma unroll
        for (int gi = 0; gi < 4; gi++)
            mx[gi] = fmaxf(mx[gi], __shfl_xor(mx[gi], msk, 64));
    float sm[4] = {0.f, 0.f, 0.f, 0.f};
    #pragma unroll
    for (int ct = 0; ct < 14; ct++) {
        bool v = (ct * 16 + n) < 197;
        #pragma unroll
        for (int gi = 0; gi < 4; gi++) {
            float p = v ? __expf(sa[ct][gi] - mx[gi]) : 0.f;
            sa[ct][gi] = p;
            sm[gi] += p;
        }
    }
    #pragma unroll
    for (int msk = 1; msk < 16; msk <<= 1)
        #pragma unroll
        for (int gi = 0; gi < 4; gi++)
            sm[gi] += __shfl_xor(sm[gi], msk, 64);
    #pragma unroll
    for (int gi = 0; gi < 4; gi++) sm[gi] = 1.f / sm[gi];

    __syncthreads();   // all waves done reading K before P overwrites KbP

    // write P (C layout -> LDS rows), rows w*16 + q*4+gi
    #pragma unroll
    for (int ct = 0; ct < 14; ct++)
        #pragma unroll
        for (int gi = 0; gi < 4; gi++)
            KbP[(w * 16 + q * 4 + gi) * VROW_ + ct * 16 + n] = f2b(sa[ct][gi] * sm[gi]);

    // O = P V  (A = P rows m=lane&15, B = Vt rows n=out col)
    f32x4 oa[4];
    #pragma unroll
    for (int nt = 0; nt < 4; nt++) oa[nt] = (f32x4){0.f, 0.f, 0.f, 0.f};
    #pragma unroll
    for (int kc = 0; kc < 7; kc++) {
        bf16x8 pf = *(const bf16x8*)&KbP[(w * 16 + n) * VROW_ + kc * 32 + q * 8];
        #pragma unroll
        for (int nt = 0; nt < 4; nt++) {
            bf16x8 vf = *(const bf16x8*)&Vt[(nt * 16 + n) * VROW_ + kc * 32 + q * 8];
            oa[nt] = __builtin_amdgcn_mfma_f32_16x16x32_bf16(pf, vf, oa[nt], 0, 0, 0);
        }
    }
    #pragma unroll
    for (int nt = 0; nt < 4; nt++) {
        #pragma unroll
        for (int gi = 0; gi < 4; gi++) {
            int row = i0 + q * 4 + gi;
            if (row < 197)
                O[((size_t)bb * 197 + row) * 768 + hh * 64 + nt * 16 + n] = f2b(oa[nt][gi]);
        }
    }
}

extern "C" void kernel_launch(void* const* d_in, const int* in_sizes, int n_in,
                              void* d_out, int out_size, void* d_ws, size_t ws_size,
                              hipStream_t stream) {
    const float* img   = (const float*)d_in[0];
    const float* plg   = (const float*)d_in[1];
    const float* plb   = (const float*)d_in[2];
    const float* Wp    = (const float*)d_in[3];
    const float* bp    = (const float*)d_in[4];
    const float* elg   = (const float*)d_in[5];
    const float* elb   = (const float*)d_in[6];
    const float* pos   = (const float*)d_in[7];
    const float* cls   = (const float*)d_in[8];
    const float* l1g   = (const float*)d_in[9];
    const float* l1b   = (const float*)d_in[10];
    const float* Wqkv  = (const float*)d_in[11];
    const float* bqkv  = (const float*)d_in[12];
    const float* Wo    = (const float*)d_in[13];
    const float* bo    = (const float*)d_in[14];
    const float* l2g   = (const float*)d_in[15];
    const float* l2b   = (const float*)d_in[16];
    const float* W1    = (const float*)d_in[17];
    const float* b1    = (const float*)d_in[18];
    const float* W2    = (const float*)d_in[19];
    const float* b2    = (const float*)d_in[20];
    const float* ng    = (const float*)d_in[21];
    const float* nb    = (const float*)d_in[22];

    char* ws = (char*)d_ws;
    float*    x    = (float*)(ws + X_OFF);
    ushort_t* h    = (ushort_t*)(ws + H_OFF);
    ushort_t* qkvb = (ushort_t*)(ws + QKVB_OFF);
    ushort_t* o    = (ushort_t*)(ws + O_OFF);
    ushort_t* mid  = (ushort_t*)(ws + MID_OFF);
    ushort_t* wt   = (ushort_t*)(ws + WT_OFF);
    uint_t*   hist = (uint_t*)(ws + HIST_OFF);
    uint_t*   h2   = (uint_t*)(ws + H2_OFF);
    float*    sums = (float*)(ws + SUMS_OFF);
    uint_t*   sel  = (uint_t*)(ws + SEL_OFF);
    float*    par  = (float*)(ws + PAR_OFF);

    hipMemsetAsync(ws + HIST_OFF, 0, SEL_OFF - HIST_OFF, stream);

    hist1_kernel<<<dim3(64, NMAT_), 256, 0, stream>>>(Wqkv, Wo, W1, W2, hist, sums);
    sel1_kernel<<<NMAT_, 256, 0, stream>>>(hist, sel);
    hist2_kernel<<<dim3(64, NMAT_), 256, 0, stream>>>(Wqkv, Wo, W1, W2, sel, h2);
    sel2_kernel<<<NMAT_, 256, 0, stream>>>(h2, sel, sums, par);

    patchify_kernel<<<M0_, 256, 0, stream>>>(img, plg, plb, h);
    trq_kernel<<<dim3(768 / 32, 768 / 32), 256, 0, stream>>>(Wp, wt, 768, 768, par, -1);
    gemm_kernel<64><<<dim3(12, 49), 256, 0, stream>>>(h, wt, bp, o, nullptr, M0_, 768, 768, 0);
    assemble_kernel<<<M_, 256, 0, stream>>>(o, cls, pos, elg, elb, x);

    for (int i = 0; i < DEPTH_; i++) {
        ln_kernel<<<M_, 256, 0, stream>>>(x, h, nullptr, l1g + i * 768, l1b + i * 768);
        trq_kernel<<<dim3(2304 / 32, 768 / 32), 256, 0, stream>>>(
            Wqkv + (size_t)i * 1769472, wt, 768, 2304, par, i);
        gemm_kernel<128><<<dim3(18, 50), 256, 0, stream>>>(h, wt, bqkv + i * 2304, qkvb,
                                                           nullptr, M_, 2304, 768, 0);
        attn_kernel<<<dim3(4, B_ * 12), 256, 0, stream>>>(qkvb, o);
        trq_kernel<<<dim3(768 / 32, 768 / 32), 256, 0, stream>>>(
            Wo + (size_t)i * 589824, wt, 768, 768, par, 12 + i);
        gemm_kernel<64><<<dim3(12, 50), 256, 0, stream>>>(o, wt, bo + i * 768, x, x,
                                                          M_, 768, 768, 2);
        ln_kernel<<<M_, 256, 0, stream>>>(x, h, nullptr, l2g + i * 768, l2b + i * 768);
        trq_kernel<<<dim3(3072 / 32, 768 / 32), 256, 0, stream>>>(
            W1 + (size_t)i * 2359296, wt, 768, 3072, par, (i < 11) ? 24 + i : -1);
        gemm_kernel<128><<<dim3(24, 50), 256, 0, stream>>>(h, wt, b1 + i * 3072, mid,
                                                           nullptr, M_, 3072, 768, 1);
        trq_kernel<<<dim3(768 / 32, 3072 / 32), 256, 0, stream>>>(
            W2 + (size_t)i * 2359296, wt, 3072, 768, par, (i < 11) ? 35 + i : -1);
        gemm_kernel<64><<<dim3(12, 50), 256, 0, stream>>>(mid, wt, b2 + i * 768, x, x,
                                                          M_, 768, 3072, 2);
    }

    ln_kernel<<<M_, 256, 0, stream>>>(x, nullptr, (float*)d_out, ng, nb);
}